// Round 9
// baseline (271.784 us; speedup 1.0000x reference)
//
#include <hip/hip_runtime.h>

#define NN 2048
#define DD 128

typedef _Float16 f16x8 __attribute__((ext_vector_type(8)));
typedef float f32x4 __attribute__((ext_vector_type(4)));

// ===========================================================================
// Fragment-tiled fp16 layout for 16x16x32 MFMA operands, matrix [R][C]:
//   tile (rt, ct) = rows rt*16..+16, cols ct*32..+32, stored as 512 fp16 at
//   blockbase = (rt*(C/32) + ct)*512; element lane*8+e holds
//   M[rt*16 + (lane&15)][ct*32 + (lane>>4)*8 + e].
// Every wave frag load/store = contiguous 1 KB.
// ===========================================================================

// ---------------------------------------------------------------------------
// prepAll: adj fp32 -> frag-tiled fp16 adjH + rdg; X -> Xt; W -> Wt.
//   bx <1024 : adjH + rdg     bx <1536 : Xt     bx <1728 : Wt
// ---------------------------------------------------------------------------
__global__ __launch_bounds__(256) void prepAll_kernel(
    const float* __restrict__ adj, _Float16* __restrict__ adjH,
    float* __restrict__ rdg, const float* __restrict__ X,
    _Float16* __restrict__ Xt, const float* __restrict__ W,
    _Float16* __restrict__ Wt) {
  __shared__ float rs[16][4];
  const int bx = blockIdx.x, tid = threadIdx.x;
  const int lane = tid & 63, wave = tid >> 6;
  const int quad = lane >> 4, l15 = lane & 15;

  if (bx < 1024) {
    const int it = bx & 127, batch = bx >> 7;
    const float* Ap = adj + ((size_t)(batch * NN) + it * 16 + l15) * NN + quad * 8;
    _Float16* Hp = adjH + (size_t)batch * NN * NN + ((size_t)it * 64) * 512 + lane * 8;
    float s = 0.f;
#pragma unroll
    for (int j = 0; j < 16; ++j) {
      const int ct = wave + 4 * j;
      float4 a0 = *(const float4*)(Ap + ct * 32);
      float4 a1 = *(const float4*)(Ap + ct * 32 + 4);
      s += ((a0.x + a0.y) + (a0.z + a0.w)) + ((a1.x + a1.y) + (a1.z + a1.w));
      f16x8 h = {(_Float16)a0.x, (_Float16)a0.y, (_Float16)a0.z, (_Float16)a0.w,
                 (_Float16)a1.x, (_Float16)a1.y, (_Float16)a1.z, (_Float16)a1.w};
      *(f16x8*)(Hp + (size_t)ct * 512) = h;
    }
    s += __shfl_xor(s, 16);
    s += __shfl_xor(s, 32);
    if (lane < 16) rs[lane][wave] = s;
    __syncthreads();
    if (tid < 16) {
      float t = rs[tid][0] + rs[tid][1] + rs[tid][2] + rs[tid][3];
      rdg[batch * NN + it * 16 + tid] = 1.0f / (t + 1.0f);
    }
  } else if (bx < 1536) {
    const int vbx = bx - 1024;
    const int batch = vbx & 7, nt = vbx >> 3;
    const size_t batA = (size_t)batch * (128 * NN);
#pragma unroll
    for (int dtl = 0; dtl < 2; ++dtl) {
      const int dt = wave * 2 + dtl;
      const float* Xp = X + ((size_t)(batch * NN) + nt * 32 + quad * 8) * DD + dt * 16 + l15;
      f16x8 v;
#pragma unroll
      for (int e = 0; e < 8; ++e) v[e] = (_Float16)Xp[(size_t)e * DD];
      *(f16x8*)(Xt + batA + ((size_t)(dt * 64 + nt)) * 512 + lane * 8) = v;
    }
  } else {
    int idx = (bx - 1536) * 256 + tid;
    int l = idx >> 14, r = idx & 16383, d = r >> 7, k = r & 127;
    Wt[idx] = (_Float16)W[l * 16384 + k * 128 + d];
  }
}

// ---------------------------------------------------------------------------
// epilogue helper: o[dout][i] += sum_k Wf-frag[dout][k] * fp16(Xs[i][k])
// ---------------------------------------------------------------------------
__device__ __forceinline__ void epiGemm(const float (*Xs)[132],
    const _Float16* __restrict__ Wf, int d0, int quad, int l15,
    f32x4 (&o)[2][2]) {
#pragma unroll
  for (int kk = 0; kk < 128; kk += 32) {
    f16x8 a0 = *(const f16x8*)(Wf + (d0 + l15) * DD + kk + quad * 8);
    f16x8 a1 = *(const f16x8*)(Wf + (d0 + 16 + l15) * DD + kk + quad * 8);
#pragma unroll
    for (int fi = 0; fi < 2; ++fi) {
      const float* xp = &Xs[fi * 16 + l15][kk + quad * 8];
      f16x8 b = {(_Float16)xp[0], (_Float16)xp[1], (_Float16)xp[2], (_Float16)xp[3],
                 (_Float16)xp[4], (_Float16)xp[5], (_Float16)xp[6], (_Float16)xp[7]};
      o[0][fi] = __builtin_amdgcn_mfma_f32_16x16x32_f16(a0, b, o[0][fi], 0, 0, 0);
      o[1][fi] = __builtin_amdgcn_mfma_f32_16x16x32_f16(a1, b, o[1][fi], 0, 0, 0);
    }
  }
}

// ---------------------------------------------------------------------------
// aggMainC (round-8 proven, unchanged): chunked-LDS-B + depth-4 reg A stream.
// ---------------------------------------------------------------------------
__device__ __forceinline__ void aggMainC(const _Float16* __restrict__ At,
    const _Float16* __restrict__ adjHb, size_t batA, size_t batB,
    int wave, int lane, int iblk, _Float16* __restrict__ Bs,
    f32x4 (&acc)[2][2]) {
  const int it0 = iblk * 2;
  const _Float16* Ap0 = At + batA + ((size_t)(2 * wave) * 64) * 512 + lane * 8;
  const _Float16* Ap1 = At + batA + ((size_t)(2 * wave + 1) * 64) * 512 + lane * 8;
  const _Float16* Bq0 = adjHb + batB + ((size_t)it0 * 64) * 512 + lane * 8;
  const _Float16* Bq1 = adjHb + batB + ((size_t)(it0 + 1) * 64) * 512 + lane * 8;

  const int t0 = wave * 4;  // this wave's 4 staging tiles (of 16 per chunk)

  f16x8 sreg[4];
#pragma unroll
  for (int j = 0; j < 4; ++j) {
    const int t = t0 + j, cl = t >> 1, rt = t & 1;
    sreg[j] = *(const f16x8*)((rt ? Bq1 : Bq0) + (size_t)cl * 512);
  }
  f16x8 qa0[4], qa1[4];
#pragma unroll
  for (int j = 0; j < 4; ++j) {
    qa0[j] = *(const f16x8*)(Ap0 + (size_t)j * 512);
    qa1[j] = *(const f16x8*)(Ap1 + (size_t)j * 512);
  }

#pragma unroll
  for (int ch = 0; ch < 8; ++ch) {
    _Float16* buf = Bs + (ch & 1) * (16 * 512);
#pragma unroll
    for (int j = 0; j < 4; ++j)
      *(f16x8*)(buf + (t0 + j) * 512 + lane * 8) = sreg[j];
    if (ch < 7) {
#pragma unroll
      for (int j = 0; j < 4; ++j) {
        const int t = t0 + j, cl = t >> 1, rt = t & 1;
        sreg[j] = *(const f16x8*)((rt ? Bq1 : Bq0) +
                                  (size_t)((ch + 1) * 8 + cl) * 512);
      }
    }
    __syncthreads();
#pragma unroll
    for (int c = 0; c < 8; ++c) {
      const int ct = ch * 8 + c;
      const int s = ct & 3;
      f16x8 b0 = *(const f16x8*)(buf + (c * 2 + 0) * 512 + lane * 8);
      f16x8 b1 = *(const f16x8*)(buf + (c * 2 + 1) * 512 + lane * 8);
      acc[0][0] = __builtin_amdgcn_mfma_f32_16x16x32_f16(qa0[s], b0, acc[0][0], 0, 0, 0);
      acc[0][1] = __builtin_amdgcn_mfma_f32_16x16x32_f16(qa0[s], b1, acc[0][1], 0, 0, 0);
      acc[1][0] = __builtin_amdgcn_mfma_f32_16x16x32_f16(qa1[s], b0, acc[1][0], 0, 0, 0);
      acc[1][1] = __builtin_amdgcn_mfma_f32_16x16x32_f16(qa1[s], b1, acc[1][1], 0, 0, 0);
      if (ct + 4 < 64) {
        qa0[s] = *(const f16x8*)(Ap0 + (size_t)(ct + 4) * 512);
        qa1[s] = *(const f16x8*)(Ap1 + (size_t)(ct + 4) * 512);
      }
    }
  }
}

// ---------------------------------------------------------------------------
// frag-tiled store of accY -> Yb via LDS bounce (Xs overlay, stride 40 fp16)
// ---------------------------------------------------------------------------
__device__ __forceinline__ void fragStoreY(float (*Xs)[132],
    const f32x4 (&accY)[2][2], _Float16* __restrict__ Yb, int i0,
    int wave, int quad, int l15, int lane, int d0) {
  __syncthreads();
  _Float16* Yst = (_Float16*)Xs;
#pragma unroll
  for (int df = 0; df < 2; ++df)
#pragma unroll
    for (int fi = 0; fi < 2; ++fi)
#pragma unroll
      for (int r = 0; r < 4; ++r)
        Yst[(d0 + df * 16 + quad * 4 + r) * 40 + fi * 16 + l15] =
            (_Float16)accY[df][fi][r];
  __syncthreads();
  const int nt = i0 >> 5;
#pragma unroll
  for (int dtl = 0; dtl < 2; ++dtl) {
    const int dt = 2 * wave + dtl;
    f16x8 v = *(const f16x8*)(&Yst[(dt * 16 + l15) * 40 + quad * 8]);
    *(f16x8*)(Yb + ((size_t)(dt * 64 + nt)) * 512 + lane * 8) = v;
  }
}

// ---------------------------------------------------------------------------
// aggC: GCN layer with chunked-LDS-B main loop.
// LDS OVERLAY: Bs (main loop, 32 KB) and Xs (epilogue, 17 KB) share one
// buffer — main loop and epilogue are barrier-separated. Static LDS ~33 KB
// -> 4 blocks/CU (was 3 at 50 KB); __launch_bounds__(256,4) pins it.
// MODE 0: epi = T@W0 -> +b,*rd,relu -> @W1 -> frag-store Yout
// MODE 1: epi = +b,*rd,relu -> @WA -> frag-store Yout
// MODE 2: epi = +b,*rd,relu -> fp32 out
// ---------------------------------------------------------------------------
template<int MODE>
__global__ __launch_bounds__(256, 4) void aggC_kernel(
    const _Float16* __restrict__ adjH, const float* __restrict__ rdg,
    const _Float16* __restrict__ At, const float* __restrict__ bias,
    const _Float16* __restrict__ WA, const _Float16* __restrict__ WB,
    _Float16* __restrict__ Yout, float* __restrict__ out) {
  __shared__ __align__(16) char smem[2 * 16 * 512 * sizeof(_Float16)];  // 32 KB
  __shared__ float bsh[128];
  __shared__ float rdsh[32];
  _Float16* Bs = (_Float16*)smem;          // main loop
  float (*Xs)[132] = (float(*)[132])smem;  // epilogue (17 KB < 32 KB)

  const int tid = threadIdx.x, bx = blockIdx.x;
  const int batch = bx & 7, iblk = bx >> 3, i0 = iblk * 32;
  const int lane = tid & 63, wave = tid >> 6;
  const int quad = lane >> 4, l15 = lane & 15, d0 = wave * 32;

  const size_t batA = (size_t)batch * (128 * NN);
  const size_t batB = (size_t)batch * ((size_t)NN * NN);

  if (tid < 128) bsh[tid] = bias[tid];
  if (tid < 32) rdsh[tid] = rdg[batch * NN + i0 + tid];

  f32x4 acc[2][2] = {};
  aggMainC(At, adjH, batA, batB, wave, lane, iblk, Bs, acc);

  __syncthreads();   // all Bs reads done -> Xs overlay safe; bsh/rdsh visible
  const float rv0 = rdsh[l15], rv1 = rdsh[16 + l15];
  f32x4 accY[2][2];

  if (MODE == 0) {
#pragma unroll
    for (int df = 0; df < 2; ++df)
#pragma unroll
      for (int fi = 0; fi < 2; ++fi)
#pragma unroll
        for (int r = 0; r < 4; ++r)
          Xs[fi * 16 + l15][d0 + df * 16 + quad * 4 + r] = acc[df][fi][r];
    __syncthreads();
    f32x4 acc2[2][2] = {};
    epiGemm(Xs, WA, d0, quad, l15, acc2);
    __syncthreads();
#pragma unroll
    for (int df = 0; df < 2; ++df)
#pragma unroll
      for (int fi = 0; fi < 2; ++fi)
#pragma unroll
        for (int r = 0; r < 4; ++r) {
          int d = d0 + df * 16 + quad * 4 + r;
          float rv = fi ? rv1 : rv0;
          Xs[fi * 16 + l15][d] = fmaxf((acc2[df][fi][r] + bsh[d]) * rv, 0.f);
        }
    __syncthreads();
    f32x4 acc3[2][2] = {};
    epiGemm(Xs, WB, d0, quad, l15, acc3);
#pragma unroll
    for (int df = 0; df < 2; ++df)
#pragma unroll
      for (int fi = 0; fi < 2; ++fi) accY[df][fi] = acc3[df][fi];
  } else {
#pragma unroll
    for (int df = 0; df < 2; ++df)
#pragma unroll
      for (int fi = 0; fi < 2; ++fi)
#pragma unroll
        for (int r = 0; r < 4; ++r) {
          int d = d0 + df * 16 + quad * 4 + r;
          float rv = fi ? rv1 : rv0;
          Xs[fi * 16 + l15][d] = fmaxf((acc[df][fi][r] + bsh[d]) * rv, 0.f);
        }
    __syncthreads();
    if (MODE == 2) {
      float* outB = out + (size_t)(batch * NN + i0) * DD;
#pragma unroll
      for (int u = 0; u < 4; ++u) {
        int c = tid + 256 * u;
        int i = c >> 5, f4 = (c & 31) * 4;
        *(float4*)(outB + (size_t)i * DD + f4) = *(const float4*)&Xs[i][f4];
      }
      return;
    }
    f32x4 acc2[2][2] = {};
    epiGemm(Xs, WA, d0, quad, l15, acc2);
#pragma unroll
    for (int df = 0; df < 2; ++df)
#pragma unroll
      for (int fi = 0; fi < 2; ++fi) accY[df][fi] = acc2[df][fi];
  }

  fragStoreY(Xs, accY, Yout + batA, i0, wave, quad, l15, lane, d0);
}

// ===========================================================================
// Legacy fallback (round-0 proven) — used when workspace < 81 MB.
// Touches only Wt (96 KB) + YtA (4 MiB at +1 MiB) in workspace.
// ===========================================================================
__global__ __launch_bounds__(256) void prep_kernel(
    const float* __restrict__ W, _Float16* __restrict__ Wt) {
  int idx = blockIdx.x * 256 + threadIdx.x;
  int l = idx >> 14, r = idx & 16383, d = r >> 7, k = r & 127;
  Wt[idx] = (_Float16)W[l * 16384 + k * 128 + d];
}

__global__ __launch_bounds__(256) void gemmY_kernel(
    const float* __restrict__ X, const _Float16* __restrict__ Wt,
    _Float16* __restrict__ Yt) {
  const int bx = blockIdx.x;
  const int batch = bx & 7, n0 = (bx >> 3) * 32;
  const int tid = threadIdx.x, lane = tid & 63, wave = tid >> 6;
  const int quad = lane >> 4, l15 = lane & 15, d0 = wave * 32;
  const float* Xb = X + (size_t)(batch * NN + n0) * DD;
  f32x4 acc[2][2] = {};
#pragma unroll
  for (int kk = 0; kk < 128; kk += 32) {
    f16x8 a0 = *(const f16x8*)(Wt + (d0 + l15) * DD + kk + quad * 8);
    f16x8 a1 = *(const f16x8*)(Wt + (d0 + 16 + l15) * DD + kk + quad * 8);
#pragma unroll
    for (int fi = 0; fi < 2; ++fi) {
      const float* xp = Xb + (size_t)(fi * 16 + l15) * DD + kk + quad * 8;
      float4 x0 = *(const float4*)xp;
      float4 x1 = *(const float4*)(xp + 4);
      f16x8 b = {(_Float16)x0.x, (_Float16)x0.y, (_Float16)x0.z, (_Float16)x0.w,
                 (_Float16)x1.x, (_Float16)x1.y, (_Float16)x1.z, (_Float16)x1.w};
      acc[0][fi] = __builtin_amdgcn_mfma_f32_16x16x32_f16(a0, b, acc[0][fi], 0, 0, 0);
      acc[1][fi] = __builtin_amdgcn_mfma_f32_16x16x32_f16(a1, b, acc[1][fi], 0, 0, 0);
    }
  }
  _Float16* YtB = Yt + (size_t)batch * DD * NN;
#pragma unroll
  for (int df = 0; df < 2; ++df)
#pragma unroll
    for (int fi = 0; fi < 2; ++fi)
#pragma unroll
      for (int r = 0; r < 4; ++r)
        YtB[(size_t)(d0 + df * 16 + quad * 4 + r) * NN + n0 + fi * 16 + l15] =
            (_Float16)acc[df][fi][r];
}

template<bool LAST>
__global__ __launch_bounds__(256) void agg_kernel(
    const float* __restrict__ adj, const _Float16* __restrict__ Yt,
    const float* __restrict__ bias, const _Float16* __restrict__ Wn,
    _Float16* __restrict__ Ytn, float* __restrict__ out) {
  __shared__ _Float16 Bsl[2][32 * 64];
  __shared__ float Xs[32][132];
  __shared__ float bsh[128];
  __shared__ float rd[32];

  const int tid = threadIdx.x, bx = blockIdx.x;
  const int batch = bx & 7, i0 = (bx >> 3) * 32;
  const int lane = tid & 63, wave = tid >> 6;
  const int quad = lane >> 4, l15 = lane & 15, d0 = wave * 32;
  const int ai = tid >> 3, ac = tid & 7;
  const int sc = ac ^ (ai & 7);

  const float* adjR = adj + (size_t)(batch * NN + i0 + ai) * NN + ac * 8;
  const _Float16* YtB = Yt + (size_t)batch * DD * NN;
  const _Float16* Ya0 = YtB + (size_t)(d0 + l15) * NN;
  const _Float16* Ya1 = YtB + (size_t)(d0 + 16 + l15) * NN;

  if (tid < 128) bsh[tid] = bias[tid];

  f32x4 acc[2][2] = {};
  float rowsum = 0.f;

  float4 av0 = *(const float4*)(adjR);
  float4 av1 = *(const float4*)(adjR + 4);
  f16x8 a[2][2];
#pragma unroll
  for (int k2 = 0; k2 < 2; ++k2) {
    a[k2][0] = *(const f16x8*)(Ya0 + k2 * 32 + quad * 8);
    a[k2][1] = *(const f16x8*)(Ya1 + k2 * 32 + quad * 8);
  }

  for (int ko = 0; ko < 32; ++ko) {
    rowsum += ((av0.x + av0.y) + (av0.z + av0.w)) + ((av1.x + av1.y) + (av1.z + av1.w));
    f16x8 h = {(_Float16)av0.x, (_Float16)av0.y, (_Float16)av0.z, (_Float16)av0.w,
               (_Float16)av1.x, (_Float16)av1.y, (_Float16)av1.z, (_Float16)av1.w};
    *(f16x8*)(&Bsl[ko & 1][ai * 64 + sc * 8]) = h;
    f16x8 an[2][2];
    if (ko < 31) {
      const int kb = (ko + 1) * 64;
      av0 = *(const float4*)(adjR + kb);
      av1 = *(const float4*)(adjR + kb + 4);
#pragma unroll
      for (int k2 = 0; k2 < 2; ++k2) {
        an[k2][0] = *(const f16x8*)(Ya0 + kb + k2 * 32 + quad * 8);
        an[k2][1] = *(const f16x8*)(Ya1 + kb + k2 * 32 + quad * 8);
      }
    }
    __syncthreads();
    const _Float16* B = Bsl[ko & 1];
#pragma unroll
    for (int k2 = 0; k2 < 2; ++k2)
#pragma unroll
      for (int fi = 0; fi < 2; ++fi) {
        const int row = fi * 16 + l15;
        const int ch = (k2 * 4 + quad) ^ (row & 7);
        f16x8 b = *(const f16x8*)(&B[row * 64 + ch * 8]);
        acc[0][fi] = __builtin_amdgcn_mfma_f32_16x16x32_f16(a[k2][0], b, acc[0][fi], 0, 0, 0);
        acc[1][fi] = __builtin_amdgcn_mfma_f32_16x16x32_f16(a[k2][1], b, acc[1][fi], 0, 0, 0);
      }
#pragma unroll
    for (int k2 = 0; k2 < 2; ++k2) { a[k2][0] = an[k2][0]; a[k2][1] = an[k2][1]; }
  }

  rowsum += __shfl_xor(rowsum, 1);
  rowsum += __shfl_xor(rowsum, 2);
  rowsum += __shfl_xor(rowsum, 4);
  if (ac == 0) rd[ai] = 1.0f / (rowsum + 1.0f);
  __syncthreads();

#pragma unroll
  for (int df = 0; df < 2; ++df)
#pragma unroll
    for (int fi = 0; fi < 2; ++fi)
#pragma unroll
      for (int r = 0; r < 4; ++r) {
        int d = d0 + df * 16 + quad * 4 + r;
        int i = fi * 16 + l15;
        Xs[i][d] = fmaxf((acc[df][fi][r] + bsh[d]) * rd[i], 0.f);
      }
  __syncthreads();

  if (LAST) {
    float* outB = out + (size_t)(batch * NN + i0) * DD;
#pragma unroll
    for (int u = 0; u < 4; ++u) {
      int c = tid + 256 * u;
      int i = c >> 5, f4 = (c & 31) * 4;
      *(float4*)(outB + (size_t)i * DD + f4) = *(const float4*)&Xs[i][f4];
    }
  } else {
    f32x4 acc2[2][2] = {};
    epiGemm(Xs, Wn, d0, quad, l15, acc2);
    _Float16* YnB = Ytn + (size_t)batch * DD * NN;
#pragma unroll
    for (int df = 0; df < 2; ++df)
#pragma unroll
      for (int fi = 0; fi < 2; ++fi)
#pragma unroll
        for (int r = 0; r < 4; ++r)
          YnB[(size_t)(d0 + df * 16 + quad * 4 + r) * NN + i0 + fi * 16 + l15] =
              (_Float16)acc2[df][fi][r];
  }
}

extern "C" void kernel_launch(void* const* d_in, const int* in_sizes, int n_in,
                              void* d_out, int out_size, void* d_ws, size_t ws_size,
                              hipStream_t stream) {
  const float* x0   = (const float*)d_in[0];   // [8,2048,128]
  const float* adj  = (const float*)d_in[1];   // [8,2048,2048]
  const float* W    = (const float*)d_in[2];   // [3,128,128]
  const float* bias = (const float*)d_in[3];   // [3,128]
  float* out = (float*)d_out;

  _Float16* Wt   = (_Float16*)d_ws;                             // 96 KB
  float*    rdg  = (float*)((char*)d_ws + (1u << 17));          // 64 KB
  _Float16* Xt   = (_Float16*)((char*)d_ws + (1u << 20));       // 4 MiB
  _Float16* Y1t  = (_Float16*)((char*)d_ws + (5u << 20));       // 4 MiB
  _Float16* Y2t  = (_Float16*)((char*)d_ws + (9u << 20));       // 4 MiB
  _Float16* adjH = (_Float16*)((char*)d_ws + (16u << 20));      // 64 MiB ends at 80 MiB

  const bool big = ws_size >= (81ull << 20);
  dim3 blk(256);

  if (big) {
    prepAll_kernel<<<1728, blk, 0, stream>>>(adj, adjH, rdg, x0, Xt, W, Wt);
    // layer 1 (W0 folded into epilogue, + fused layer-2 Linear)
    aggC_kernel<0><<<512, blk, 0, stream>>>(adjH, rdg, Xt, bias, Wt, Wt + 16384, Y1t, nullptr);
    // layer 2 (+ fused layer-3 Linear)
    aggC_kernel<1><<<512, blk, 0, stream>>>(adjH, rdg, Y1t, bias + 128, Wt + 32768, nullptr, Y2t, nullptr);
    // layer 3 -> fp32 out
    aggC_kernel<2><<<512, blk, 0, stream>>>(adjH, rdg, Y2t, bias + 256, nullptr, nullptr, nullptr, out);
  } else {
    _Float16* YtA  = Xt;
    _Float16* YtB_ = (_Float16*)d_out;
    prep_kernel<<<192, blk, 0, stream>>>(W, Wt);
    gemmY_kernel<<<512, blk, 0, stream>>>(x0, Wt, YtA);
    agg_kernel<false><<<512, blk, 0, stream>>>(adj, YtA,  bias,       Wt + 16384, YtB_, nullptr);
    agg_kernel<false><<<512, blk, 0, stream>>>(adj, YtB_, bias + 128, Wt + 32768, YtA,  nullptr);
    agg_kernel<true ><<<512, blk, 0, stream>>>(adj, YtA,  bias + 256, nullptr,    nullptr, out);
  }
}

// Round 10
// 267.611 us; speedup vs baseline: 1.0156x; 1.0156x over previous
//
#include <hip/hip_runtime.h>

#define NN 2048
#define DD 128

typedef _Float16 f16x8 __attribute__((ext_vector_type(8)));
typedef float f32x4 __attribute__((ext_vector_type(4)));

// ===========================================================================
// Fragment-tiled fp16 layout for 16x16x32 MFMA operands, matrix [R][C]:
//   tile (rt, ct) = rows rt*16..+16, cols ct*32..+32, stored as 512 fp16 at
//   blockbase = (rt*(C/32) + ct)*512; element lane*8+e holds
//   M[rt*16 + (lane&15)][ct*32 + (lane>>4)*8 + e].
// ===========================================================================

// ---------------------------------------------------------------------------
// prepX: X fp32 -> frag-tiled fp16 Xt (bx<512); W -> Wt (bx<704). Tiny.
// ---------------------------------------------------------------------------
__global__ __launch_bounds__(256) void prepX_kernel(
    const float* __restrict__ X, _Float16* __restrict__ Xt,
    const float* __restrict__ W, _Float16* __restrict__ Wt) {
  const int bx = blockIdx.x, tid = threadIdx.x;
  const int lane = tid & 63, wave = tid >> 6;
  const int quad = lane >> 4, l15 = lane & 15;
  if (bx < 512) {
    const int batch = bx & 7, nt = bx >> 3;
    const size_t batA = (size_t)batch * (128 * NN);
#pragma unroll
    for (int dtl = 0; dtl < 2; ++dtl) {
      const int dt = wave * 2 + dtl;
      const float* Xp = X + ((size_t)(batch * NN) + nt * 32 + quad * 8) * DD + dt * 16 + l15;
      f16x8 v;
#pragma unroll
      for (int e = 0; e < 8; ++e) v[e] = (_Float16)Xp[(size_t)e * DD];
      *(f16x8*)(Xt + batA + ((size_t)(dt * 64 + nt)) * 512 + lane * 8) = v;
    }
  } else {
    int idx = (bx - 512) * 256 + tid;
    int l = idx >> 14, r = idx & 16383, d = r >> 7, k = r & 127;
    Wt[idx] = (_Float16)W[l * 16384 + k * 128 + d];
  }
}

// ---------------------------------------------------------------------------
// epilogue helper: o[dout][i] += sum_k Wf-frag[dout][k] * fp16(Xs[i][k])
// ---------------------------------------------------------------------------
__device__ __forceinline__ void epiGemm(const float (*Xs)[132],
    const _Float16* __restrict__ Wf, int d0, int quad, int l15,
    f32x4 (&o)[2][2]) {
#pragma unroll
  for (int kk = 0; kk < 128; kk += 32) {
    f16x8 a0 = *(const f16x8*)(Wf + (d0 + l15) * DD + kk + quad * 8);
    f16x8 a1 = *(const f16x8*)(Wf + (d0 + 16 + l15) * DD + kk + quad * 8);
#pragma unroll
    for (int fi = 0; fi < 2; ++fi) {
      const float* xp = &Xs[fi * 16 + l15][kk + quad * 8];
      f16x8 b = {(_Float16)xp[0], (_Float16)xp[1], (_Float16)xp[2], (_Float16)xp[3],
                 (_Float16)xp[4], (_Float16)xp[5], (_Float16)xp[6], (_Float16)xp[7]};
      o[0][fi] = __builtin_amdgcn_mfma_f32_16x16x32_f16(a0, b, o[0][fi], 0, 0, 0);
      o[1][fi] = __builtin_amdgcn_mfma_f32_16x16x32_f16(a1, b, o[1][fi], 0, 0, 0);
    }
  }
}

// ---------------------------------------------------------------------------
// aggMainC (round-8 proven, unchanged): chunked-LDS-B + depth-4 reg A stream.
// ---------------------------------------------------------------------------
__device__ __forceinline__ void aggMainC(const _Float16* __restrict__ At,
    const _Float16* __restrict__ adjHb, size_t batA, size_t batB,
    int wave, int lane, int iblk, _Float16* __restrict__ Bs,
    f32x4 (&acc)[2][2]) {
  const int it0 = iblk * 2;
  const _Float16* Ap0 = At + batA + ((size_t)(2 * wave) * 64) * 512 + lane * 8;
  const _Float16* Ap1 = At + batA + ((size_t)(2 * wave + 1) * 64) * 512 + lane * 8;
  const _Float16* Bq0 = adjHb + batB + ((size_t)it0 * 64) * 512 + lane * 8;
  const _Float16* Bq1 = adjHb + batB + ((size_t)(it0 + 1) * 64) * 512 + lane * 8;

  const int t0 = wave * 4;

  f16x8 sreg[4];
#pragma unroll
  for (int j = 0; j < 4; ++j) {
    const int t = t0 + j, cl = t >> 1, rt = t & 1;
    sreg[j] = *(const f16x8*)((rt ? Bq1 : Bq0) + (size_t)cl * 512);
  }
  f16x8 qa0[4], qa1[4];
#pragma unroll
  for (int j = 0; j < 4; ++j) {
    qa0[j] = *(const f16x8*)(Ap0 + (size_t)j * 512);
    qa1[j] = *(const f16x8*)(Ap1 + (size_t)j * 512);
  }

#pragma unroll
  for (int ch = 0; ch < 8; ++ch) {
    _Float16* buf = Bs + (ch & 1) * (16 * 512);
#pragma unroll
    for (int j = 0; j < 4; ++j)
      *(f16x8*)(buf + (t0 + j) * 512 + lane * 8) = sreg[j];
    if (ch < 7) {
#pragma unroll
      for (int j = 0; j < 4; ++j) {
        const int t = t0 + j, cl = t >> 1, rt = t & 1;
        sreg[j] = *(const f16x8*)((rt ? Bq1 : Bq0) +
                                  (size_t)((ch + 1) * 8 + cl) * 512);
      }
    }
    __syncthreads();
#pragma unroll
    for (int c = 0; c < 8; ++c) {
      const int ct = ch * 8 + c;
      const int s = ct & 3;
      f16x8 b0 = *(const f16x8*)(buf + (c * 2 + 0) * 512 + lane * 8);
      f16x8 b1 = *(const f16x8*)(buf + (c * 2 + 1) * 512 + lane * 8);
      acc[0][0] = __builtin_amdgcn_mfma_f32_16x16x32_f16(qa0[s], b0, acc[0][0], 0, 0, 0);
      acc[0][1] = __builtin_amdgcn_mfma_f32_16x16x32_f16(qa0[s], b1, acc[0][1], 0, 0, 0);
      acc[1][0] = __builtin_amdgcn_mfma_f32_16x16x32_f16(qa1[s], b0, acc[1][0], 0, 0, 0);
      acc[1][1] = __builtin_amdgcn_mfma_f32_16x16x32_f16(qa1[s], b1, acc[1][1], 0, 0, 0);
      if (ct + 4 < 64) {
        qa0[s] = *(const f16x8*)(Ap0 + (size_t)(ct + 4) * 512);
        qa1[s] = *(const f16x8*)(Ap1 + (size_t)(ct + 4) * 512);
      }
    }
  }
}

// ---------------------------------------------------------------------------
// frag-tiled store of accY -> Yb via LDS bounce (Xs overlay, stride 40 fp16)
// ---------------------------------------------------------------------------
__device__ __forceinline__ void fragStoreY(float (*Xs)[132],
    const f32x4 (&accY)[2][2], _Float16* __restrict__ Yb, int i0,
    int wave, int quad, int l15, int lane, int d0) {
  __syncthreads();
  _Float16* Yst = (_Float16*)Xs;
#pragma unroll
  for (int df = 0; df < 2; ++df)
#pragma unroll
    for (int fi = 0; fi < 2; ++fi)
#pragma unroll
      for (int r = 0; r < 4; ++r)
        Yst[(d0 + df * 16 + quad * 4 + r) * 40 + fi * 16 + l15] =
            (_Float16)accY[df][fi][r];
  __syncthreads();
  const int nt = i0 >> 5;
#pragma unroll
  for (int dtl = 0; dtl < 2; ++dtl) {
    const int dt = 2 * wave + dtl;
    f16x8 v = *(const f16x8*)(&Yst[(dt * 16 + l15) * 40 + quad * 8]);
    *(f16x8*)(Yb + ((size_t)(dt * 64 + nt)) * 512 + lane * 8) = v;
  }
}

// ---------------------------------------------------------------------------
// aggF: LAYER 1 with adj fp32 consumed DIRECTLY (no prepAll adj pass).
// Staging converts fp32->fp16 in-register, writes the frag tile to LDS AND
// to adjH (for layers 2/3), and folds the rowsums (rdg becomes write-only).
// Same chunk/barrier/MFMA skeleton as aggMainC.
// Epilogue: T@W0 -> +b,*rd,relu -> @W1 -> frag-store Y1t.
// ---------------------------------------------------------------------------
__global__ __launch_bounds__(256, 4) void aggF_kernel(
    const float* __restrict__ adj, _Float16* __restrict__ adjH,
    float* __restrict__ rdg, const _Float16* __restrict__ Xt,
    const float* __restrict__ bias, const _Float16* __restrict__ W0f,
    const _Float16* __restrict__ W1f, _Float16* __restrict__ Y1t) {
  __shared__ __align__(16) char smem[2 * 16 * 512 * sizeof(_Float16)];  // 32 KB
  __shared__ float bsh[128];
  __shared__ float rdsh[32];
  __shared__ float rs2[2][16][4];
  _Float16* Bs = (_Float16*)smem;
  float (*Xs)[132] = (float(*)[132])smem;

  const int tid = threadIdx.x, bx = blockIdx.x;
  const int batch = bx & 7, iblk = bx >> 3, i0 = iblk * 32;
  const int lane = tid & 63, wave = tid >> 6;
  const int quad = lane >> 4, l15 = lane & 15, d0 = wave * 32;
  const size_t batA = (size_t)batch * (128 * NN);
  const size_t batB = (size_t)batch * ((size_t)NN * NN);
  const int it0 = iblk * 2;

  if (tid < 128) bsh[tid] = bias[tid];

  const _Float16* Ap0 = Xt + batA + ((size_t)(2 * wave) * 64) * 512 + lane * 8;
  const _Float16* Ap1 = Xt + batA + ((size_t)(2 * wave + 1) * 64) * 512 + lane * 8;

  // B source: adj fp32, rows i0..i0+32. Wave's tile j: rt=j&1, cl=2*wave+(j>>1)
  const float* AdjB = adj + ((size_t)(batch * NN + i0)) * NN;
  const float* rp[4];
#pragma unroll
  for (int j = 0; j < 4; ++j)
    rp[j] = AdjB + (size_t)((j & 1) * 16 + l15) * NN + (2 * wave + (j >> 1)) * 32 + quad * 8;

  const int t0 = wave * 4;
  float rsum0 = 0.f, rsum1 = 0.f;
  float4 sa[4], sb[4];
  f16x8 qa0[4], qa1[4];

#pragma unroll
  for (int j = 0; j < 4; ++j) { sa[j] = *(const float4*)(rp[j]); sb[j] = *(const float4*)(rp[j] + 4); }
#pragma unroll
  for (int j = 0; j < 4; ++j) {
    qa0[j] = *(const f16x8*)(Ap0 + (size_t)j * 512);
    qa1[j] = *(const f16x8*)(Ap1 + (size_t)j * 512);
  }

  f32x4 acc[2][2] = {};

#pragma unroll
  for (int ch = 0; ch < 8; ++ch) {
    _Float16* buf = Bs + (ch & 1) * (16 * 512);
#pragma unroll
    for (int j = 0; j < 4; ++j) {
      float4 a0 = sa[j], a1 = sb[j];
      float s = ((a0.x + a0.y) + (a0.z + a0.w)) + ((a1.x + a1.y) + (a1.z + a1.w));
      if (j & 1) rsum1 += s; else rsum0 += s;
      f16x8 h = {(_Float16)a0.x, (_Float16)a0.y, (_Float16)a0.z, (_Float16)a0.w,
                 (_Float16)a1.x, (_Float16)a1.y, (_Float16)a1.z, (_Float16)a1.w};
      *(f16x8*)(buf + (t0 + j) * 512 + lane * 8) = h;
      // side-effect: frag-tiled adjH for layers 2/3
      *(f16x8*)(adjH + batB +
                ((size_t)((it0 + (j & 1)) * 64 + ch * 8 + 2 * wave + (j >> 1))) * 512 +
                lane * 8) = h;
    }
    if (ch < 7) {
#pragma unroll
      for (int j = 0; j < 4; ++j) {
        sa[j] = *(const float4*)(rp[j] + (ch + 1) * 256);
        sb[j] = *(const float4*)(rp[j] + (ch + 1) * 256 + 4);
      }
    }
    __syncthreads();
#pragma unroll
    for (int c = 0; c < 8; ++c) {
      const int ct = ch * 8 + c;
      const int s = ct & 3;
      f16x8 b0 = *(const f16x8*)(buf + (c * 2 + 0) * 512 + lane * 8);
      f16x8 b1 = *(const f16x8*)(buf + (c * 2 + 1) * 512 + lane * 8);
      acc[0][0] = __builtin_amdgcn_mfma_f32_16x16x32_f16(qa0[s], b0, acc[0][0], 0, 0, 0);
      acc[0][1] = __builtin_amdgcn_mfma_f32_16x16x32_f16(qa0[s], b1, acc[0][1], 0, 0, 0);
      acc[1][0] = __builtin_amdgcn_mfma_f32_16x16x32_f16(qa1[s], b0, acc[1][0], 0, 0, 0);
      acc[1][1] = __builtin_amdgcn_mfma_f32_16x16x32_f16(qa1[s], b1, acc[1][1], 0, 0, 0);
      if (ct + 4 < 64) {
        qa0[s] = *(const f16x8*)(Ap0 + (size_t)(ct + 4) * 512);
        qa1[s] = *(const f16x8*)(Ap1 + (size_t)(ct + 4) * 512);
      }
    }
  }

  // rowsums: butterfly over the 4 quads (same row, different col slices)
  rsum0 += __shfl_xor(rsum0, 16);
  rsum0 += __shfl_xor(rsum0, 32);
  rsum1 += __shfl_xor(rsum1, 16);
  rsum1 += __shfl_xor(rsum1, 32);
  if (lane < 16) { rs2[0][lane][wave] = rsum0; rs2[1][lane][wave] = rsum1; }
  __syncthreads();   // rs2 + all Bs reads done (Xs overlay safe)
  if (tid < 32) {
    const int rt = tid >> 4, r = tid & 15;
    float t = rs2[rt][r][0] + rs2[rt][r][1] + rs2[rt][r][2] + rs2[rt][r][3];
    float v = 1.0f / (t + 1.0f);
    rdsh[tid] = v;
    rdg[batch * NN + i0 + tid] = v;
  }

  // epilogue: T -> Xs raw -> @W0 -> relu -> @W1 -> Y1t
#pragma unroll
  for (int df = 0; df < 2; ++df)
#pragma unroll
    for (int fi = 0; fi < 2; ++fi)
#pragma unroll
      for (int r = 0; r < 4; ++r)
        Xs[fi * 16 + l15][d0 + df * 16 + quad * 4 + r] = acc[df][fi][r];
  __syncthreads();
  f32x4 acc2[2][2] = {};
  epiGemm(Xs, W0f, d0, quad, l15, acc2);
  __syncthreads();
  const float rv0 = rdsh[l15], rv1 = rdsh[16 + l15];
#pragma unroll
  for (int df = 0; df < 2; ++df)
#pragma unroll
    for (int fi = 0; fi < 2; ++fi)
#pragma unroll
      for (int r = 0; r < 4; ++r) {
        int d = d0 + df * 16 + quad * 4 + r;
        float rv = fi ? rv1 : rv0;
        Xs[fi * 16 + l15][d] = fmaxf((acc2[df][fi][r] + bsh[d]) * rv, 0.f);
      }
  __syncthreads();
  f32x4 acc3[2][2] = {};
  epiGemm(Xs, W1f, d0, quad, l15, acc3);
  fragStoreY(Xs, acc3, Y1t + batA, i0, wave, quad, l15, lane, d0);
}

// ---------------------------------------------------------------------------
// aggC (round-8 proven): layers 2/3, fp16 frag adjH input.
// MODE 1: epi = +b,*rd,relu -> @WA -> frag-store Yout
// MODE 2: epi = +b,*rd,relu -> fp32 out
// ---------------------------------------------------------------------------
template<int MODE>
__global__ __launch_bounds__(256, 4) void aggC_kernel(
    const _Float16* __restrict__ adjH, const float* __restrict__ rdg,
    const _Float16* __restrict__ At, const float* __restrict__ bias,
    const _Float16* __restrict__ WA, _Float16* __restrict__ Yout,
    float* __restrict__ out) {
  __shared__ __align__(16) char smem[2 * 16 * 512 * sizeof(_Float16)];  // 32 KB
  __shared__ float bsh[128];
  __shared__ float rdsh[32];
  _Float16* Bs = (_Float16*)smem;
  float (*Xs)[132] = (float(*)[132])smem;

  const int tid = threadIdx.x, bx = blockIdx.x;
  const int batch = bx & 7, iblk = bx >> 3, i0 = iblk * 32;
  const int lane = tid & 63, wave = tid >> 6;
  const int quad = lane >> 4, l15 = lane & 15, d0 = wave * 32;

  const size_t batA = (size_t)batch * (128 * NN);
  const size_t batB = (size_t)batch * ((size_t)NN * NN);

  if (tid < 128) bsh[tid] = bias[tid];
  if (tid < 32) rdsh[tid] = rdg[batch * NN + i0 + tid];

  f32x4 acc[2][2] = {};
  aggMainC(At, adjH, batA, batB, wave, lane, iblk, Bs, acc);

  __syncthreads();   // Bs reads done -> Xs overlay safe; bsh/rdsh visible
  const float rv0 = rdsh[l15], rv1 = rdsh[16 + l15];

#pragma unroll
  for (int df = 0; df < 2; ++df)
#pragma unroll
    for (int fi = 0; fi < 2; ++fi)
#pragma unroll
      for (int r = 0; r < 4; ++r) {
        int d = d0 + df * 16 + quad * 4 + r;
        float rv = fi ? rv1 : rv0;
        Xs[fi * 16 + l15][d] = fmaxf((acc[df][fi][r] + bsh[d]) * rv, 0.f);
      }
  __syncthreads();
  if (MODE == 2) {
    float* outB = out + (size_t)(batch * NN + i0) * DD;
#pragma unroll
    for (int u = 0; u < 4; ++u) {
      int c = tid + 256 * u;
      int i = c >> 5, f4 = (c & 31) * 4;
      *(float4*)(outB + (size_t)i * DD + f4) = *(const float4*)&Xs[i][f4];
    }
    return;
  }
  f32x4 acc2[2][2] = {};
  epiGemm(Xs, WA, d0, quad, l15, acc2);
  fragStoreY(Xs, acc2, Yout + batA, i0, wave, quad, l15, lane, d0);
}

// ===========================================================================
// Legacy fallback (round-0 proven) — used when workspace < 81 MB.
// ===========================================================================
__global__ __launch_bounds__(256) void prep_kernel(
    const float* __restrict__ W, _Float16* __restrict__ Wt) {
  int idx = blockIdx.x * 256 + threadIdx.x;
  int l = idx >> 14, r = idx & 16383, d = r >> 7, k = r & 127;
  Wt[idx] = (_Float16)W[l * 16384 + k * 128 + d];
}

__global__ __launch_bounds__(256) void gemmY_kernel(
    const float* __restrict__ X, const _Float16* __restrict__ Wt,
    _Float16* __restrict__ Yt) {
  const int bx = blockIdx.x;
  const int batch = bx & 7, n0 = (bx >> 3) * 32;
  const int tid = threadIdx.x, lane = tid & 63, wave = tid >> 6;
  const int quad = lane >> 4, l15 = lane & 15, d0 = wave * 32;
  const float* Xb = X + (size_t)(batch * NN + n0) * DD;
  f32x4 acc[2][2] = {};
#pragma unroll
  for (int kk = 0; kk < 128; kk += 32) {
    f16x8 a0 = *(const f16x8*)(Wt + (d0 + l15) * DD + kk + quad * 8);
    f16x8 a1 = *(const f16x8*)(Wt + (d0 + 16 + l15) * DD + kk + quad * 8);
#pragma unroll
    for (int fi = 0; fi < 2; ++fi) {
      const float* xp = Xb + (size_t)(fi * 16 + l15) * DD + kk + quad * 8;
      float4 x0 = *(const float4*)xp;
      float4 x1 = *(const float4*)(xp + 4);
      f16x8 b = {(_Float16)x0.x, (_Float16)x0.y, (_Float16)x0.z, (_Float16)x0.w,
                 (_Float16)x1.x, (_Float16)x1.y, (_Float16)x1.z, (_Float16)x1.w};
      acc[0][fi] = __builtin_amdgcn_mfma_f32_16x16x32_f16(a0, b, acc[0][fi], 0, 0, 0);
      acc[1][fi] = __builtin_amdgcn_mfma_f32_16x16x32_f16(a1, b, acc[1][fi], 0, 0, 0);
    }
  }
  _Float16* YtB = Yt + (size_t)batch * DD * NN;
#pragma unroll
  for (int df = 0; df < 2; ++df)
#pragma unroll
    for (int fi = 0; fi < 2; ++fi)
#pragma unroll
      for (int r = 0; r < 4; ++r)
        YtB[(size_t)(d0 + df * 16 + quad * 4 + r) * NN + n0 + fi * 16 + l15] =
            (_Float16)acc[df][fi][r];
}

template<bool LAST>
__global__ __launch_bounds__(256) void agg_kernel(
    const float* __restrict__ adj, const _Float16* __restrict__ Yt,
    const float* __restrict__ bias, const _Float16* __restrict__ Wn,
    _Float16* __restrict__ Ytn, float* __restrict__ out) {
  __shared__ _Float16 Bsl[2][32 * 64];
  __shared__ float Xs[32][132];
  __shared__ float bsh[128];
  __shared__ float rd[32];

  const int tid = threadIdx.x, bx = blockIdx.x;
  const int batch = bx & 7, i0 = (bx >> 3) * 32;
  const int lane = tid & 63, wave = tid >> 6;
  const int quad = lane >> 4, l15 = lane & 15, d0 = wave * 32;
  const int ai = tid >> 3, ac = tid & 7;
  const int sc = ac ^ (ai & 7);

  const float* adjR = adj + (size_t)(batch * NN + i0 + ai) * NN + ac * 8;
  const _Float16* YtB = Yt + (size_t)batch * DD * NN;
  const _Float16* Ya0 = YtB + (size_t)(d0 + l15) * NN;
  const _Float16* Ya1 = YtB + (size_t)(d0 + 16 + l15) * NN;

  if (tid < 128) bsh[tid] = bias[tid];

  f32x4 acc[2][2] = {};
  float rowsum = 0.f;

  float4 av0 = *(const float4*)(adjR);
  float4 av1 = *(const float4*)(adjR + 4);
  f16x8 a[2][2];
#pragma unroll
  for (int k2 = 0; k2 < 2; ++k2) {
    a[k2][0] = *(const f16x8*)(Ya0 + k2 * 32 + quad * 8);
    a[k2][1] = *(const f16x8*)(Ya1 + k2 * 32 + quad * 8);
  }

  for (int ko = 0; ko < 32; ++ko) {
    rowsum += ((av0.x + av0.y) + (av0.z + av0.w)) + ((av1.x + av1.y) + (av1.z + av1.w));
    f16x8 h = {(_Float16)av0.x, (_Float16)av0.y, (_Float16)av0.z, (_Float16)av0.w,
               (_Float16)av1.x, (_Float16)av1.y, (_Float16)av1.z, (_Float16)av1.w};
    *(f16x8*)(&Bsl[ko & 1][ai * 64 + sc * 8]) = h;
    f16x8 an[2][2];
    if (ko < 31) {
      const int kb = (ko + 1) * 64;
      av0 = *(const float4*)(adjR + kb);
      av1 = *(const float4*)(adjR + kb + 4);
#pragma unroll
      for (int k2 = 0; k2 < 2; ++k2) {
        an[k2][0] = *(const f16x8*)(Ya0 + kb + k2 * 32 + quad * 8);
        an[k2][1] = *(const f16x8*)(Ya1 + kb + k2 * 32 + quad * 8);
      }
    }
    __syncthreads();
    const _Float16* B = Bsl[ko & 1];
#pragma unroll
    for (int k2 = 0; k2 < 2; ++k2)
#pragma unroll
      for (int fi = 0; fi < 2; ++fi) {
        const int row = fi * 16 + l15;
        const int ch = (k2 * 4 + quad) ^ (row & 7);
        f16x8 b = *(const f16x8*)(&B[row * 64 + ch * 8]);
        acc[0][fi] = __builtin_amdgcn_mfma_f32_16x16x32_f16(a[k2][0], b, acc[0][fi], 0, 0, 0);
        acc[1][fi] = __builtin_amdgcn_mfma_f32_16x16x32_f16(a[k2][1], b, acc[1][fi], 0, 0, 0);
      }
#pragma unroll
    for (int k2 = 0; k2 < 2; ++k2) { a[k2][0] = an[k2][0]; a[k2][1] = an[k2][1]; }
  }

  rowsum += __shfl_xor(rowsum, 1);
  rowsum += __shfl_xor(rowsum, 2);
  rowsum += __shfl_xor(rowsum, 4);
  if (ac == 0) rd[ai] = 1.0f / (rowsum + 1.0f);
  __syncthreads();

#pragma unroll
  for (int df = 0; df < 2; ++df)
#pragma unroll
    for (int fi = 0; fi < 2; ++fi)
#pragma unroll
      for (int r = 0; r < 4; ++r) {
        int d = d0 + df * 16 + quad * 4 + r;
        int i = fi * 16 + l15;
        Xs[i][d] = fmaxf((acc[df][fi][r] + bsh[d]) * rd[i], 0.f);
      }
  __syncthreads();

  if (LAST) {
    float* outB = out + (size_t)(batch * NN + i0) * DD;
#pragma unroll
    for (int u = 0; u < 4; ++u) {
      int c = tid + 256 * u;
      int i = c >> 5, f4 = (c & 31) * 4;
      *(float4*)(outB + (size_t)i * DD + f4) = *(const float4*)&Xs[i][f4];
    }
  } else {
    f32x4 acc2[2][2] = {};
    epiGemm(Xs, Wn, d0, quad, l15, acc2);
    _Float16* YnB = Ytn + (size_t)batch * DD * NN;
#pragma unroll
    for (int df = 0; df < 2; ++df)
#pragma unroll
      for (int fi = 0; fi < 2; ++fi)
#pragma unroll
        for (int r = 0; r < 4; ++r)
          YnB[(size_t)(d0 + df * 16 + quad * 4 + r) * NN + i0 + fi * 16 + l15] =
              (_Float16)acc2[df][fi][r];
  }
}

extern "C" void kernel_launch(void* const* d_in, const int* in_sizes, int n_in,
                              void* d_out, int out_size, void* d_ws, size_t ws_size,
                              hipStream_t stream) {
  const float* x0   = (const float*)d_in[0];   // [8,2048,128]
  const float* adj  = (const float*)d_in[1];   // [8,2048,2048]
  const float* W    = (const float*)d_in[2];   // [3,128,128]
  const float* bias = (const float*)d_in[3];   // [3,128]
  float* out = (float*)d_out;

  _Float16* Wt   = (_Float16*)d_ws;                             // 96 KB
  float*    rdg  = (float*)((char*)d_ws + (1u << 17));          // 64 KB
  _Float16* Xt   = (_Float16*)((char*)d_ws + (1u << 20));       // 4 MiB
  _Float16* Y1t  = (_Float16*)((char*)d_ws + (5u << 20));       // 4 MiB
  _Float16* Y2t  = (_Float16*)((char*)d_ws + (9u << 20));       // 4 MiB
  _Float16* adjH = (_Float16*)((char*)d_ws + (16u << 20));      // 64 MiB ends at 80 MiB

  const bool big = ws_size >= (81ull << 20);
  dim3 blk(256);

  if (big) {
    prepX_kernel<<<704, blk, 0, stream>>>(x0, Xt, W, Wt);
    // layer 1: consumes adj fp32 directly, emits adjH + rdg, fused W0/W1
    aggF_kernel<<<512, blk, 0, stream>>>(adj, adjH, rdg, Xt, bias, Wt, Wt + 16384, Y1t);
    // layer 2 (+ fused layer-3 Linear)
    aggC_kernel<1><<<512, blk, 0, stream>>>(adjH, rdg, Y1t, bias + 128, Wt + 32768, Y2t, nullptr);
    // layer 3 -> fp32 out
    aggC_kernel<2><<<512, blk, 0, stream>>>(adjH, rdg, Y2t, bias + 256, nullptr, nullptr, out);
  } else {
    _Float16* YtA  = Xt;
    _Float16* YtB_ = (_Float16*)d_out;
    prep_kernel<<<192, blk, 0, stream>>>(W, Wt);
    gemmY_kernel<<<512, blk, 0, stream>>>(x0, Wt, YtA);
    agg_kernel<false><<<512, blk, 0, stream>>>(adj, YtA,  bias,       Wt + 16384, YtB_, nullptr);
    agg_kernel<false><<<512, blk, 0, stream>>>(adj, YtB_, bias + 128, Wt + 32768, YtA,  nullptr);
    agg_kernel<true ><<<512, blk, 0, stream>>>(adj, YtA,  bias + 256, nullptr,    nullptr, out);
  }
}